// Round 1
// baseline (1666.310 us; speedup 1.0000x reference)
//
#include <hip/hip_runtime.h>
#include <math.h>

// Problem constants (fixed by reference)
//  L_MAX=3, N_MAX=8, N_RAW=16, Q=4, N_SPECIES=4, N_STRUCT=40, feat=4096, hidden=256
static constexpr float RCf = 5.0f;
static constexpr float PIf = 3.14159265358979323846f;

// ---------------------------------------------------------------------------
// Kernel 1: per-pair expansion, atomically accumulated into
//   cS[atom_i][s][lm][n]  (s = species of j), 4000 x 4 x 16 x 8 f32
// ---------------------------------------------------------------------------
__global__ __launch_bounds__(256) void pair_kernel(
    const float* __restrict__ pos, const int* __restrict__ pairs,
    const int* __restrict__ species, const float* __restrict__ W_rad,
    float* __restrict__ cS, int n_pairs)
{
    __shared__ float wr_sh[512];              // W_rad (4,16,8)
    int t = threadIdx.x;
    wr_sh[t]       = W_rad[t];
    wr_sh[t + 256] = W_rad[t + 256];
    __syncthreads();

    int p = blockIdx.x * 256 + t;
    if (p >= n_pairs) return;
    int i = pairs[2 * p], j = pairs[2 * p + 1];

    float dx = pos[3 * j]     - pos[3 * i];
    float dy = pos[3 * j + 1] - pos[3 * i + 1];
    float dz = pos[3 * j + 2] - pos[3 * i + 2];
    float r = sqrtf(dx * dx + dy * dy + dz * dz + 1e-12f);
    if (r >= RCf) return;                     // fcut == 0 -> zero contribution
    float inv = 1.0f / r;
    float x = dx * inv, y = dy * inv, z = dz * inv;
    float fcut = 0.5f * (cosf((PIf / RCf) * r) + 1.0f);

    // R[l][n] = sum_r raw[r] * W_rad[l][r][n]
    float R[4][8];
#pragma unroll
    for (int l = 0; l < 4; l++)
#pragma unroll
        for (int n = 0; n < 8; n++) R[l][n] = 0.0f;

#pragma unroll
    for (int rr = 0; rr < 16; rr++) {
        float mu = (RCf / 15.0f) * (float)rr;           // linspace(0,5,16)
        float tt = (r - mu) * (16.0f / RCf);            // sigma = RC/16
        float w = expf(-tt * tt) * fcut;
#pragma unroll
        for (int l = 0; l < 4; l++) {
            const float* wr = &wr_sh[(l * 16 + rr) * 8];
#pragma unroll
            for (int n = 0; n < 8; n++)
                R[l][n] = fmaf(w, wr[n], R[l][n]);
        }
    }

    // spherical harmonics (16)
    float x2 = x * x, y2 = y * y, z2 = z * z;
    float Y[16];
    Y[0]  = 0.28209479177387814f;
    Y[1]  = 0.4886025119029199f * y;
    Y[2]  = 0.4886025119029199f * z;
    Y[3]  = 0.4886025119029199f * x;
    Y[4]  = 1.0925484305920792f * x * y;
    Y[5]  = 1.0925484305920792f * y * z;
    Y[6]  = 0.31539156525252005f * (3.0f * z2 - 1.0f);
    Y[7]  = 1.0925484305920792f * x * z;
    Y[8]  = 0.5462742152960396f * (x2 - y2);
    Y[9]  = 0.5900435899266435f * y * (3.0f * x2 - y2);
    Y[10] = 2.890611442640554f * x * y * z;
    Y[11] = 0.4570457994644658f * y * (5.0f * z2 - 1.0f);
    Y[12] = 0.3731763325901154f * z * (5.0f * z2 - 3.0f);
    Y[13] = 0.4570457994644658f * x * (5.0f * z2 - 1.0f);
    Y[14] = 1.445305721320277f * z * (x2 - y2);
    Y[15] = 0.5900435899266435f * x * (x2 - 3.0f * y2);

    const int LOF[16] = {0,1,1,1,2,2,2,2,2,3,3,3,3,3,3,3};
    int s = species[j];
    float* dst = cS + ((size_t)i * 4 + s) * 128;
#pragma unroll
    for (int lm = 0; lm < 16; lm++) {
        float yl = Y[lm];
        const float* Rl = R[LOF[lm]];
#pragma unroll
        for (int n = 0; n < 8; n++)
            atomicAdd(dst + lm * 8 + n, yl * Rl[n]);
    }
}

// ---------------------------------------------------------------------------
// Kernel 2: per-atom (one block of 256 per atom):
//   c[a][lm][n] = sum_s W_alch[s][a] * cS[s][lm][n]
//   f[l*1024 + a*256 + b*64 + n*8 + k] = sum_m c[a][l^2+m][n]*c[b][l^2+m][k]/sqrt(2l+1)
//   LayerNorm(f) -> F (4000 x 4096)
// ---------------------------------------------------------------------------
__global__ __launch_bounds__(256) void atom_kernel(
    const float* __restrict__ cS, const float* __restrict__ W_alch,
    const float* __restrict__ gamma, const float* __restrict__ beta,
    float* __restrict__ F, int n_atoms)
{
    int atom = blockIdx.x;
    __shared__ float sin_[512];
    __shared__ float csh[512];
    __shared__ float red[8];
    int t = threadIdx.x;

    sin_[t]       = cS[(size_t)atom * 512 + t];
    sin_[t + 256] = cS[(size_t)atom * 512 + t + 256];
    __syncthreads();

#pragma unroll
    for (int rep = 0; rep < 2; rep++) {
        int idx = rep * 256 + t;
        int a = idx >> 7, rest = idx & 127;
        float acc = 0.0f;
#pragma unroll
        for (int s = 0; s < 4; s++)
            acc = fmaf(W_alch[s * 4 + a], sin_[s * 128 + rest], acc);
        csh[idx] = acc;
    }
    __syncthreads();

    const float invsq[4] = {1.0f, 0.57735026918962576f, 0.44721359549995794f,
                            0.37796447300922722f};
    int b = t >> 6, n = (t >> 3) & 7, k = t & 7;
    float fv[16];
    float lsum = 0.0f;
#pragma unroll
    for (int ii = 0; ii < 16; ii++) {
        int l = ii >> 2, a = ii & 3;
        int base = l * l;
        float acc = 0.0f;
        int cnt = 2 * l + 1;
        for (int m = 0; m < cnt; m++)
            acc = fmaf(csh[a * 128 + (base + m) * 8 + n],
                       csh[b * 128 + (base + m) * 8 + k], acc);
        acc *= invsq[l];
        fv[ii] = acc;
        lsum += acc;
    }

    // block reduce: mean
    float v = lsum;
#pragma unroll
    for (int off = 1; off < 64; off <<= 1) v += __shfl_xor(v, off, 64);
    int wid = t >> 6, lane = t & 63;
    if (lane == 0) red[wid] = v;
    __syncthreads();
    float mean = (red[0] + red[1] + red[2] + red[3]) * (1.0f / 4096.0f);

    // block reduce: variance (two-pass for stability)
    float lss = 0.0f;
#pragma unroll
    for (int ii = 0; ii < 16; ii++) {
        float d = fv[ii] - mean;
        lss += d * d;
    }
    v = lss;
#pragma unroll
    for (int off = 1; off < 64; off <<= 1) v += __shfl_xor(v, off, 64);
    if (lane == 0) red[4 + wid] = v;
    __syncthreads();
    float var = (red[4] + red[5] + red[6] + red[7]) * (1.0f / 4096.0f);
    float rs = rsqrtf(var + 1e-5f);

    float* Fo = F + (size_t)atom * 4096;
#pragma unroll
    for (int ii = 0; ii < 16; ii++) {
        int idx = ii * 256 + t;
        Fo[idx] = (fv[ii] - mean) * rs * gamma[idx] + beta[idx];
    }
}

// ---------------------------------------------------------------------------
// Kernel 3: batched f32 GEMM + silu epilogue.
//   C[q][m][h] = silu(scale(m,q) * sum_k A[q][m][k] * B[q][k][h]),  N fixed 256
//   useAlch: scale = W_alch[species[m]][q], else 1
//   64x64 tile, 256 threads, 4x4 per thread, K-tile 16
// ---------------------------------------------------------------------------
__global__ __launch_bounds__(256) void gemm_silu(
    const float* __restrict__ A, const float* __restrict__ B, float* __restrict__ C,
    int M, int K, long sAq, long sBq, long sCq,
    const int* __restrict__ species, const float* __restrict__ W_alch, int useAlch)
{
    constexpr int N = 256;
    int q = blockIdx.z;
    const float* Aq = A + (size_t)q * sAq;
    const float* Bq = B + (size_t)q * sBq;
    float* Cq = C + (size_t)q * sCq;

    __shared__ float As[16][68];   // [k][m]
    __shared__ float Bs[16][68];   // [k][n]
    int tid = threadIdx.x;
    int tx = tid & 15, ty = tid >> 4;
    int bm = blockIdx.x * 64, bn = blockIdx.y * 64;
    float acc[4][4] = {};

    int am = tid >> 2, akc = tid & 3;        // A: 64 rows x (4 chunks of 4 k)
    int bk = tid >> 4, bn4 = (tid & 15) * 4; // B: 16 k-rows x 64 cols

    for (int k0 = 0; k0 < K; k0 += 16) {
        float4 av;
        int arow = bm + am;
        if (arow < M)
            av = *reinterpret_cast<const float4*>(&Aq[(size_t)arow * K + k0 + akc * 4]);
        else
            av = make_float4(0.f, 0.f, 0.f, 0.f);
        float4 bv = *reinterpret_cast<const float4*>(&Bq[(size_t)(k0 + bk) * N + bn + bn4]);

        As[akc * 4 + 0][am] = av.x;
        As[akc * 4 + 1][am] = av.y;
        As[akc * 4 + 2][am] = av.z;
        As[akc * 4 + 3][am] = av.w;
        *reinterpret_cast<float4*>(&Bs[bk][bn4]) = bv;
        __syncthreads();

#pragma unroll
        for (int kk = 0; kk < 16; kk++) {
            float4 a4 = *reinterpret_cast<const float4*>(&As[kk][ty * 4]);
            float4 b4 = *reinterpret_cast<const float4*>(&Bs[kk][tx * 4]);
            float a[4] = {a4.x, a4.y, a4.z, a4.w};
            float b[4] = {b4.x, b4.y, b4.z, b4.w};
#pragma unroll
            for (int i2 = 0; i2 < 4; i2++)
#pragma unroll
                for (int j2 = 0; j2 < 4; j2++)
                    acc[i2][j2] = fmaf(a[i2], b[j2], acc[i2][j2]);
        }
        __syncthreads();
    }

#pragma unroll
    for (int i2 = 0; i2 < 4; i2++) {
        int row = bm + ty * 4 + i2;
        if (row >= M) continue;
        float scale = 1.0f;
        if (useAlch) scale = W_alch[species[row] * 4 + q];
        float tmp[4];
#pragma unroll
        for (int j2 = 0; j2 < 4; j2++) {
            float vv = acc[i2][j2] * scale;
            tmp[j2] = vv / (1.0f + expf(-vv));   // silu
        }
        *reinterpret_cast<float4*>(&Cq[(size_t)row * N + bn + tx * 4]) =
            make_float4(tmp[0], tmp[1], tmp[2], tmp[3]);
    }
}

// ---------------------------------------------------------------------------
// Kernel 4: e[n] = sum_q H2[q][n][:] . W_last[q][:], += comp_w, segment-sum
//   one wave per atom; result scaled by 0.5 (= 1/sqrt(Q))
// ---------------------------------------------------------------------------
__global__ __launch_bounds__(256) void final_kernel(
    const float* __restrict__ H2, const float* __restrict__ W_last,
    const float* __restrict__ comp_w, const int* __restrict__ species,
    const int* __restrict__ sid, float* __restrict__ out, int n_atoms)
{
    int wid = threadIdx.x >> 6, lane = threadIdx.x & 63;
    int atom = blockIdx.x * 4 + wid;
    if (atom >= n_atoms) return;
    float acc = 0.0f;
#pragma unroll
    for (int q = 0; q < 4; q++) {
        const float* h = H2 + ((size_t)q * n_atoms + atom) * 256;
#pragma unroll
        for (int c = 0; c < 4; c++) {
            int hh = c * 64 + lane;
            acc = fmaf(h[hh], W_last[q * 256 + hh], acc);
        }
    }
#pragma unroll
    for (int off = 1; off < 64; off <<= 1) acc += __shfl_xor(acc, off, 64);
    if (lane == 0) {
        float vv = acc + comp_w[species[atom]];
        atomicAdd(&out[sid[atom]], vv * 0.5f);
    }
}

// ---------------------------------------------------------------------------
extern "C" void kernel_launch(void* const* d_in, const int* in_sizes, int n_in,
                              void* d_out, int out_size, void* d_ws, size_t ws_size,
                              hipStream_t stream)
{
    const float* pos     = (const float*)d_in[0];
    const int*   pairs   = (const int*)d_in[1];
    const int*   species = (const int*)d_in[2];
    const int*   sid     = (const int*)d_in[3];
    const float* W_rad   = (const float*)d_in[4];
    const float* W_alch  = (const float*)d_in[5];
    const float* gamma   = (const float*)d_in[6];
    const float* beta    = (const float*)d_in[7];
    const float* W1      = (const float*)d_in[8];
    const float* W2      = (const float*)d_in[9];
    const float* W_last  = (const float*)d_in[10];
    const float* comp_w  = (const float*)d_in[11];

    int n_atoms = in_sizes[0] / 3;
    int n_pairs = in_sizes[1] / 2;
    float* out = (float*)d_out;

    char* ws = (char*)d_ws;
    size_t csB = (size_t)n_atoms * 512 * sizeof(float);        // 8.2 MB
    size_t fB  = (size_t)n_atoms * 4096 * sizeof(float);       // 65.5 MB
    size_t hB  = (size_t)4 * n_atoms * 256 * sizeof(float);    // 16.4 MB
    float* cS = (float*)ws;
    float* F  = (float*)(ws + csB);
    float* H1 = (float*)(ws + csB + fB);
    float* H2 = (float*)(ws + csB + fB + hB);

    hipMemsetAsync(cS, 0, csB, stream);
    hipMemsetAsync(out, 0, (size_t)out_size * sizeof(float), stream);

    pair_kernel<<<(n_pairs + 255) / 256, 256, 0, stream>>>(
        pos, pairs, species, W_rad, cS, n_pairs);

    atom_kernel<<<n_atoms, 256, 0, stream>>>(cS, W_alch, gamma, beta, F, n_atoms);

    dim3 g1((n_atoms + 63) / 64, 4, 4);
    // GEMM1: F (4000x4096) @ W1[q] (4096x256) -> H1[q], epilogue silu(alch * .)
    gemm_silu<<<g1, 256, 0, stream>>>(F, W1, H1, n_atoms, 4096,
                                      0L, 4096L * 256, (long)n_atoms * 256,
                                      species, W_alch, 1);
    // GEMM2: H1[q] (4000x256) @ W2[q] (256x256) -> H2[q], epilogue silu
    gemm_silu<<<g1, 256, 0, stream>>>(H1, W2, H2, n_atoms, 256,
                                      (long)n_atoms * 256, 256L * 256, (long)n_atoms * 256,
                                      species, W_alch, 0);

    final_kernel<<<(n_atoms + 3) / 4, 256, 0, stream>>>(
        H2, W_last, comp_w, species, sid, out, n_atoms);
}

// Round 2
// 648.784 us; speedup vs baseline: 2.5684x; 2.5684x over previous
//
#include <hip/hip_runtime.h>
#include <math.h>

// Problem constants (fixed by reference)
//  L_MAX=3, N_MAX=8, N_RAW=16, Q=4, N_SPECIES=4, N_STRUCT=40, feat=4096, hidden=256
static constexpr float RCf = 5.0f;
static constexpr float PIf = 3.14159265358979323846f;

// ---------------------------------------------------------------------------
// CSR build: count -> scan -> fill
// ---------------------------------------------------------------------------
__global__ __launch_bounds__(256) void count_kernel(
    const int* __restrict__ pairs, int* __restrict__ cnt, int n_pairs)
{
    int p = blockIdx.x * 256 + threadIdx.x;
    if (p < n_pairs) atomicAdd(&cnt[pairs[2 * p]], 1);
}

// single block, 256 threads, handles up to 4096 atoms
__global__ __launch_bounds__(256) void scan_kernel(
    const int* __restrict__ cnt, int* __restrict__ off, int n_atoms)
{
    __shared__ int part[256];
    int t = threadIdx.x;
    const int per = 16;
    int base = t * per;
    int local[16];
    int s = 0;
#pragma unroll
    for (int k = 0; k < per; k++) {
        int v = (base + k < n_atoms) ? cnt[base + k] : 0;
        local[k] = s;
        s += v;
    }
    part[t] = s;
    __syncthreads();
    // Hillis-Steele inclusive scan over 256 partials
    for (int d = 1; d < 256; d <<= 1) {
        int v = (t >= d) ? part[t - d] : 0;
        __syncthreads();
        part[t] += v;
        __syncthreads();
    }
    int pre = (t == 0) ? 0 : part[t - 1];
#pragma unroll
    for (int k = 0; k < per; k++)
        if (base + k < n_atoms) off[base + k] = pre + local[k];
}

__global__ __launch_bounds__(256) void fill_kernel(
    const int* __restrict__ pairs, const int* __restrict__ off,
    int* __restrict__ cursor, int* __restrict__ idx, int n_pairs)
{
    int p = blockIdx.x * 256 + threadIdx.x;
    if (p >= n_pairs) return;
    int i = pairs[2 * p];
    int slot = atomicAdd(&cursor[i], 1);
    idx[off[i] + slot] = p;
}

// ---------------------------------------------------------------------------
// Fused gather + power-spectrum + LayerNorm. One block (256 threads) per atom.
//   c[a][lm][n] = sum_{pairs p of atom} W_alch[s_j][a] * Y[lm] * R[l(lm)][n]
//   f -> LayerNorm -> F (4000 x 4096)
// ---------------------------------------------------------------------------
__global__ __launch_bounds__(256) void gather_atom_kernel(
    const float* __restrict__ pos, const int* __restrict__ pairs,
    const int* __restrict__ species, const float* __restrict__ W_rad,
    const float* __restrict__ W_alch, const int* __restrict__ off,
    const int* __restrict__ idx, const float* __restrict__ gamma,
    const float* __restrict__ beta, float* __restrict__ F,
    int n_atoms, int n_pairs)
{
    int atom = blockIdx.x;
    int t = threadIdx.x;
    __shared__ float wr2[512];        // W_rad transposed: [rr][n][l]
    __shared__ float raw_sh[16][16];  // [pair][rr]
    __shared__ float Y_sh[16][16];    // [pair][lm]
    __shared__ float wal_sh[16][4];   // [pair][a]
    __shared__ float part[2][512];
    __shared__ float c_sh[512];       // [a][lm][n]
    __shared__ float red[8];

    // stage W_rad transposed: src (l,rr,n) -> wr2[rr*32 + n*4 + l]
    for (int u = t; u < 512; u += 256) {
        int l = u >> 7, rr = (u >> 3) & 15, n = u & 7;
        wr2[rr * 32 + n * 4 + l] = W_rad[u];
    }

    int p0 = off[atom];
    int p1 = (atom + 1 < n_atoms) ? off[atom + 1] : n_pairs;
    int npair = p1 - p0;

    float px = pos[3 * atom], py = pos[3 * atom + 1], pz = pos[3 * atom + 2];

    int half = t >> 7, e = t & 127;
    int lm = e >> 3, nn = e & 7;
    int l_of = (lm > 0) + (lm > 3) + (lm > 8);
    float acc0 = 0.f, acc1 = 0.f, acc2 = 0.f, acc3 = 0.f;

    __syncthreads();  // wr2 ready

    for (int done = 0; done < npair; done += 16) {
        int pp = t >> 4, sub = t & 15;
        // ---- phase A1: geometry + raw + Y + walch for 16 pairs ----
        {
            int k = done + pp;
            float xx = 0.f, yy = 0.f, zz = 0.f;
            int sj = 0;
            if (k < npair) {
                int pid = idx[p0 + k];
                int j = pairs[2 * pid + 1];
                sj = species[j];
                float dx = pos[3 * j]     - px;
                float dy = pos[3 * j + 1] - py;
                float dz = pos[3 * j + 2] - pz;
                float r = sqrtf(dx * dx + dy * dy + dz * dz + 1e-12f);
                float inv = 1.0f / r;
                xx = dx * inv; yy = dy * inv; zz = dz * inv;
                float fc = (r < RCf) ? 0.5f * (cosf((PIf / RCf) * r) + 1.0f) : 0.0f;
                float mu = (RCf / 15.0f) * (float)sub;
                float tt = (r - mu) * (16.0f / RCf);
                raw_sh[pp][sub] = expf(-tt * tt) * fc;
            } else {
                raw_sh[pp][sub] = 0.0f;
            }
            float x2 = xx * xx, y2 = yy * yy, z2 = zz * zz;
            float yv;
            switch (sub) {
                case 0:  yv = 0.28209479177387814f; break;
                case 1:  yv = 0.4886025119029199f * yy; break;
                case 2:  yv = 0.4886025119029199f * zz; break;
                case 3:  yv = 0.4886025119029199f * xx; break;
                case 4:  yv = 1.0925484305920792f * xx * yy; break;
                case 5:  yv = 1.0925484305920792f * yy * zz; break;
                case 6:  yv = 0.31539156525252005f * (3.0f * z2 - 1.0f); break;
                case 7:  yv = 1.0925484305920792f * xx * zz; break;
                case 8:  yv = 0.5462742152960396f * (x2 - y2); break;
                case 9:  yv = 0.5900435899266435f * yy * (3.0f * x2 - y2); break;
                case 10: yv = 2.890611442640554f * xx * yy * zz; break;
                case 11: yv = 0.4570457994644658f * yy * (5.0f * z2 - 1.0f); break;
                case 12: yv = 0.3731763325901154f * zz * (5.0f * z2 - 3.0f); break;
                case 13: yv = 0.4570457994644658f * xx * (5.0f * z2 - 1.0f); break;
                case 14: yv = 1.445305721320277f * zz * (x2 - y2); break;
                default: yv = 0.5900435899266435f * xx * (x2 - 3.0f * y2); break;
            }
            Y_sh[pp][sub] = yv;
            if (sub < 4) wal_sh[pp][sub] = W_alch[sj * 4 + sub];
        }
        __syncthreads();
        // ---- phase A2: accumulate 8 pairs per half ----
        int base = half * 8;
#pragma unroll
        for (int pq = 0; pq < 8; pq++) {
            int pp2 = base + pq;
            float Re = 0.f;
            const float* rw = raw_sh[pp2];
            const float* wv = &wr2[nn * 4 + l_of];
#pragma unroll
            for (int rr = 0; rr < 16; rr++)
                Re = fmaf(rw[rr], wv[rr * 32], Re);
            float contrib = Y_sh[pp2][lm] * Re;
            const float* wa = wal_sh[pp2];
            acc0 = fmaf(wa[0], contrib, acc0);
            acc1 = fmaf(wa[1], contrib, acc1);
            acc2 = fmaf(wa[2], contrib, acc2);
            acc3 = fmaf(wa[3], contrib, acc3);
        }
        __syncthreads();
    }

    part[half][0 * 128 + e] = acc0;
    part[half][1 * 128 + e] = acc1;
    part[half][2 * 128 + e] = acc2;
    part[half][3 * 128 + e] = acc3;
    __syncthreads();
    c_sh[t]       = part[0][t]       + part[1][t];
    c_sh[t + 256] = part[0][t + 256] + part[1][t + 256];
    __syncthreads();

    // ---- phase B: power spectrum + LayerNorm ----
    const float invsq[4] = {1.0f, 0.57735026918962576f, 0.44721359549995794f,
                            0.37796447300922722f};
    int b = t >> 6, n = (t >> 3) & 7, k = t & 7;
    float fv[16];
    float lsum = 0.0f;
#pragma unroll
    for (int ii = 0; ii < 16; ii++) {
        int l = ii >> 2, a = ii & 3;
        int base = l * l;
        float acc = 0.0f;
        int cntm = 2 * l + 1;
        for (int m = 0; m < cntm; m++)
            acc = fmaf(c_sh[a * 128 + (base + m) * 8 + n],
                       c_sh[b * 128 + (base + m) * 8 + k], acc);
        acc *= invsq[l];
        fv[ii] = acc;
        lsum += acc;
    }

    float v = lsum;
#pragma unroll
    for (int o = 1; o < 64; o <<= 1) v += __shfl_xor(v, o, 64);
    int wid = t >> 6, lane = t & 63;
    if (lane == 0) red[wid] = v;
    __syncthreads();
    float mean = (red[0] + red[1] + red[2] + red[3]) * (1.0f / 4096.0f);

    float lss = 0.0f;
#pragma unroll
    for (int ii = 0; ii < 16; ii++) {
        float d = fv[ii] - mean;
        lss += d * d;
    }
    v = lss;
#pragma unroll
    for (int o = 1; o < 64; o <<= 1) v += __shfl_xor(v, o, 64);
    if (lane == 0) red[4 + wid] = v;
    __syncthreads();
    float var = (red[4] + red[5] + red[6] + red[7]) * (1.0f / 4096.0f);
    float rs = rsqrtf(var + 1e-5f);

    float* Fo = F + (size_t)atom * 4096;
#pragma unroll
    for (int ii = 0; ii < 16; ii++) {
        int ix = ii * 256 + t;
        Fo[ix] = (fv[ii] - mean) * rs * gamma[ix] + beta[ix];
    }
}

// ---------------------------------------------------------------------------
// Batched f32 GEMM + silu epilogue (unchanged from round 0)
// ---------------------------------------------------------------------------
__global__ __launch_bounds__(256) void gemm_silu(
    const float* __restrict__ A, const float* __restrict__ B, float* __restrict__ C,
    int M, int K, long sAq, long sBq, long sCq,
    const int* __restrict__ species, const float* __restrict__ W_alch, int useAlch)
{
    constexpr int N = 256;
    int q = blockIdx.z;
    const float* Aq = A + (size_t)q * sAq;
    const float* Bq = B + (size_t)q * sBq;
    float* Cq = C + (size_t)q * sCq;

    __shared__ float As[16][68];
    __shared__ float Bs[16][68];
    int tid = threadIdx.x;
    int tx = tid & 15, ty = tid >> 4;
    int bm = blockIdx.x * 64, bn = blockIdx.y * 64;
    float acc[4][4] = {};

    int am = tid >> 2, akc = tid & 3;
    int bk = tid >> 4, bn4 = (tid & 15) * 4;

    for (int k0 = 0; k0 < K; k0 += 16) {
        float4 av;
        int arow = bm + am;
        if (arow < M)
            av = *reinterpret_cast<const float4*>(&Aq[(size_t)arow * K + k0 + akc * 4]);
        else
            av = make_float4(0.f, 0.f, 0.f, 0.f);
        float4 bv = *reinterpret_cast<const float4*>(&Bq[(size_t)(k0 + bk) * N + bn + bn4]);

        As[akc * 4 + 0][am] = av.x;
        As[akc * 4 + 1][am] = av.y;
        As[akc * 4 + 2][am] = av.z;
        As[akc * 4 + 3][am] = av.w;
        *reinterpret_cast<float4*>(&Bs[bk][bn4]) = bv;
        __syncthreads();

#pragma unroll
        for (int kk = 0; kk < 16; kk++) {
            float4 a4 = *reinterpret_cast<const float4*>(&As[kk][ty * 4]);
            float4 b4 = *reinterpret_cast<const float4*>(&Bs[kk][tx * 4]);
            float a[4] = {a4.x, a4.y, a4.z, a4.w};
            float b[4] = {b4.x, b4.y, b4.z, b4.w};
#pragma unroll
            for (int i2 = 0; i2 < 4; i2++)
#pragma unroll
                for (int j2 = 0; j2 < 4; j2++)
                    acc[i2][j2] = fmaf(a[i2], b[j2], acc[i2][j2]);
        }
        __syncthreads();
    }

#pragma unroll
    for (int i2 = 0; i2 < 4; i2++) {
        int row = bm + ty * 4 + i2;
        if (row >= M) continue;
        float scale = 1.0f;
        if (useAlch) scale = W_alch[species[row] * 4 + q];
        float tmp[4];
#pragma unroll
        for (int j2 = 0; j2 < 4; j2++) {
            float vv = acc[i2][j2] * scale;
            tmp[j2] = vv / (1.0f + expf(-vv));
        }
        *reinterpret_cast<float4*>(&Cq[(size_t)row * N + bn + tx * 4]) =
            make_float4(tmp[0], tmp[1], tmp[2], tmp[3]);
    }
}

// ---------------------------------------------------------------------------
// Final: e[n] = sum_q H2[q][n][:].W_last[q][:], += comp_w, segment-sum, *0.5
// ---------------------------------------------------------------------------
__global__ __launch_bounds__(256) void final_kernel(
    const float* __restrict__ H2, const float* __restrict__ W_last,
    const float* __restrict__ comp_w, const int* __restrict__ species,
    const int* __restrict__ sid, float* __restrict__ out, int n_atoms)
{
    int wid = threadIdx.x >> 6, lane = threadIdx.x & 63;
    int atom = blockIdx.x * 4 + wid;
    if (atom >= n_atoms) return;
    float acc = 0.0f;
#pragma unroll
    for (int q = 0; q < 4; q++) {
        const float* h = H2 + ((size_t)q * n_atoms + atom) * 256;
#pragma unroll
        for (int c = 0; c < 4; c++) {
            int hh = c * 64 + lane;
            acc = fmaf(h[hh], W_last[q * 256 + hh], acc);
        }
    }
#pragma unroll
    for (int o = 1; o < 64; o <<= 1) acc += __shfl_xor(acc, o, 64);
    if (lane == 0) {
        float vv = acc + comp_w[species[atom]];
        atomicAdd(&out[sid[atom]], vv * 0.5f);
    }
}

// ---------------------------------------------------------------------------
extern "C" void kernel_launch(void* const* d_in, const int* in_sizes, int n_in,
                              void* d_out, int out_size, void* d_ws, size_t ws_size,
                              hipStream_t stream)
{
    const float* pos     = (const float*)d_in[0];
    const int*   pairs   = (const int*)d_in[1];
    const int*   species = (const int*)d_in[2];
    const int*   sid     = (const int*)d_in[3];
    const float* W_rad   = (const float*)d_in[4];
    const float* W_alch  = (const float*)d_in[5];
    const float* gamma   = (const float*)d_in[6];
    const float* beta    = (const float*)d_in[7];
    const float* W1      = (const float*)d_in[8];
    const float* W2      = (const float*)d_in[9];
    const float* W_last  = (const float*)d_in[10];
    const float* comp_w  = (const float*)d_in[11];

    int n_atoms = in_sizes[0] / 3;
    int n_pairs = in_sizes[1] / 2;
    float* out = (float*)d_out;

    char* ws = (char*)d_ws;
    int*   cnt    = (int*)(ws);                     // 16 KB
    int*   cursor = (int*)(ws + 16384);             // 16 KB
    int*   off    = (int*)(ws + 32768);             // 16.4 KB
    int*   idx    = (int*)(ws + 51200);             // 640 KB
    float* F      = (float*)(ws + 691200);          // 65.5 MB
    float* H1     = (float*)(ws + 691200 + (size_t)n_atoms * 4096 * 4);
    float* H2     = (float*)(ws + 691200 + (size_t)n_atoms * 4096 * 4
                                        + (size_t)4 * n_atoms * 256 * 4);

    hipMemsetAsync(cnt, 0, 32768, stream);   // cnt + cursor
    hipMemsetAsync(out, 0, (size_t)out_size * sizeof(float), stream);

    count_kernel<<<(n_pairs + 255) / 256, 256, 0, stream>>>(pairs, cnt, n_pairs);
    scan_kernel<<<1, 256, 0, stream>>>(cnt, off, n_atoms);
    fill_kernel<<<(n_pairs + 255) / 256, 256, 0, stream>>>(pairs, off, cursor, idx, n_pairs);

    gather_atom_kernel<<<n_atoms, 256, 0, stream>>>(
        pos, pairs, species, W_rad, W_alch, off, idx, gamma, beta, F,
        n_atoms, n_pairs);

    dim3 g1((n_atoms + 63) / 64, 4, 4);
    gemm_silu<<<g1, 256, 0, stream>>>(F, W1, H1, n_atoms, 4096,
                                      0L, 4096L * 256, (long)n_atoms * 256,
                                      species, W_alch, 1);
    gemm_silu<<<g1, 256, 0, stream>>>(H1, W2, H2, n_atoms, 256,
                                      (long)n_atoms * 256, 256L * 256, (long)n_atoms * 256,
                                      species, W_alch, 0);

    final_kernel<<<(n_atoms + 3) / 4, 256, 0, stream>>>(
        H2, W_last, comp_w, species, sid, out, n_atoms);
}

// Round 3
// 206.646 us; speedup vs baseline: 8.0636x; 3.1396x over previous
//
#include <hip/hip_runtime.h>
#include <math.h>

typedef __attribute__((ext_vector_type(8))) short short8v;
typedef __attribute__((ext_vector_type(4))) float f32x4;

static constexpr float RCf = 5.0f;
static constexpr float PIf = 3.14159265358979323846f;

__device__ inline unsigned short f2bf(float f) {
    union { float f; unsigned u; } x; x.f = f;
    unsigned u = x.u;
    unsigned r = (u + 0x7fffu + ((u >> 16) & 1u)) >> 16;
    return (unsigned short)r;
}

// ---------------------------------------------------------------------------
// CSR build: count -> scan -> fill
// ---------------------------------------------------------------------------
__global__ __launch_bounds__(256) void count_kernel(
    const int* __restrict__ pairs, int* __restrict__ cnt, int n_pairs)
{
    int p = blockIdx.x * 256 + threadIdx.x;
    if (p < n_pairs) atomicAdd(&cnt[pairs[2 * p]], 1);
}

__global__ __launch_bounds__(256) void scan_kernel(
    const int* __restrict__ cnt, int* __restrict__ off, int n_atoms)
{
    __shared__ int part[256];
    int t = threadIdx.x;
    const int per = 16;
    int base = t * per;
    int local[16];
    int s = 0;
#pragma unroll
    for (int k = 0; k < per; k++) {
        int v = (base + k < n_atoms) ? cnt[base + k] : 0;
        local[k] = s;
        s += v;
    }
    part[t] = s;
    __syncthreads();
    for (int d = 1; d < 256; d <<= 1) {
        int v = (t >= d) ? part[t - d] : 0;
        __syncthreads();
        part[t] += v;
        __syncthreads();
    }
    int pre = (t == 0) ? 0 : part[t - 1];
#pragma unroll
    for (int k = 0; k < per; k++)
        if (base + k < n_atoms) off[base + k] = pre + local[k];
}

__global__ __launch_bounds__(256) void fill_kernel(
    const int* __restrict__ pairs, const int* __restrict__ off,
    int* __restrict__ cursor, int* __restrict__ idx, int n_pairs)
{
    int p = blockIdx.x * 256 + threadIdx.x;
    if (p >= n_pairs) return;
    int i = pairs[2 * p];
    int slot = atomicAdd(&cursor[i], 1);
    idx[off[i] + slot] = p;
}

// ---------------------------------------------------------------------------
// Transpose + bf16 cast: W [q][K][N] f32 -> WT [(q*N + n)][K] bf16
// grid: (K/64, N/64, q), 256 threads
// ---------------------------------------------------------------------------
__global__ __launch_bounds__(256) void transpose_w(
    const float* __restrict__ W, unsigned short* __restrict__ WT, int K, int N)
{
    __shared__ float tile[64][65];
    int q = blockIdx.z;
    int k0 = blockIdx.x * 64, n0 = blockIdx.y * 64;
    const float* Wq = W + (size_t)q * K * N;
    int t = threadIdx.x;
    int kl = t >> 6, nl = t & 63;
#pragma unroll
    for (int i = 0; i < 16; i++)
        tile[kl + i * 4][nl] = Wq[(size_t)(k0 + kl + i * 4) * N + n0 + nl];
    __syncthreads();
    int nr = t >> 2, kc = (t & 3) * 16;
    unsigned short* dst = WT + ((size_t)q * N + n0 + nr) * K + k0 + kc;
    short8v v0, v1;
#pragma unroll
    for (int i = 0; i < 8; i++) {
        v0[i] = (short)f2bf(tile[kc + i][nr]);
        v1[i] = (short)f2bf(tile[kc + 8 + i][nr]);
    }
    *(short8v*)(dst) = v0;
    *(short8v*)(dst + 8) = v1;
}

// ---------------------------------------------------------------------------
// Fused gather + power-spectrum + LayerNorm -> bf16 F. One block per atom.
// ---------------------------------------------------------------------------
__global__ __launch_bounds__(256) void gather_atom_kernel(
    const float* __restrict__ pos, const int* __restrict__ pairs,
    const int* __restrict__ species, const float* __restrict__ W_rad,
    const float* __restrict__ W_alch, const int* __restrict__ off,
    const int* __restrict__ idx, const float* __restrict__ gamma,
    const float* __restrict__ beta, unsigned short* __restrict__ F,
    int n_atoms, int n_pairs)
{
    int atom = blockIdx.x;
    int t = threadIdx.x;
    __shared__ float wr2[512];        // W_rad transposed: [rr][n][l]
    __shared__ float raw_sh[16][16];
    __shared__ float Y_sh[16][16];
    __shared__ float wal_sh[16][4];
    __shared__ float part[2][512];
    __shared__ float c_sh[512];
    __shared__ float red[8];

    for (int u = t; u < 512; u += 256) {
        int l = u >> 7, rr = (u >> 3) & 15, n = u & 7;
        wr2[rr * 32 + n * 4 + l] = W_rad[u];
    }

    int p0 = off[atom];
    int p1 = (atom + 1 < n_atoms) ? off[atom + 1] : n_pairs;
    int npair = p1 - p0;

    float px = pos[3 * atom], py = pos[3 * atom + 1], pz = pos[3 * atom + 2];

    int half = t >> 7, e = t & 127;
    int lm = e >> 3, nn = e & 7;
    int l_of = (lm > 0) + (lm > 3) + (lm > 8);
    float acc0 = 0.f, acc1 = 0.f, acc2 = 0.f, acc3 = 0.f;

    __syncthreads();

    for (int done = 0; done < npair; done += 16) {
        int pp = t >> 4, sub = t & 15;
        {
            int k = done + pp;
            float xx = 0.f, yy = 0.f, zz = 0.f;
            int sj = 0;
            if (k < npair) {
                int pid = idx[p0 + k];
                int j = pairs[2 * pid + 1];
                sj = species[j];
                float dx = pos[3 * j]     - px;
                float dy = pos[3 * j + 1] - py;
                float dz = pos[3 * j + 2] - pz;
                float r = sqrtf(dx * dx + dy * dy + dz * dz + 1e-12f);
                float inv = 1.0f / r;
                xx = dx * inv; yy = dy * inv; zz = dz * inv;
                float fc = (r < RCf) ? 0.5f * (cosf((PIf / RCf) * r) + 1.0f) : 0.0f;
                float mu = (RCf / 15.0f) * (float)sub;
                float tt = (r - mu) * (16.0f / RCf);
                raw_sh[pp][sub] = expf(-tt * tt) * fc;
            } else {
                raw_sh[pp][sub] = 0.0f;
            }
            float x2 = xx * xx, y2 = yy * yy, z2 = zz * zz;
            float yv;
            switch (sub) {
                case 0:  yv = 0.28209479177387814f; break;
                case 1:  yv = 0.4886025119029199f * yy; break;
                case 2:  yv = 0.4886025119029199f * zz; break;
                case 3:  yv = 0.4886025119029199f * xx; break;
                case 4:  yv = 1.0925484305920792f * xx * yy; break;
                case 5:  yv = 1.0925484305920792f * yy * zz; break;
                case 6:  yv = 0.31539156525252005f * (3.0f * z2 - 1.0f); break;
                case 7:  yv = 1.0925484305920792f * xx * zz; break;
                case 8:  yv = 0.5462742152960396f * (x2 - y2); break;
                case 9:  yv = 0.5900435899266435f * yy * (3.0f * x2 - y2); break;
                case 10: yv = 2.890611442640554f * xx * yy * zz; break;
                case 11: yv = 0.4570457994644658f * yy * (5.0f * z2 - 1.0f); break;
                case 12: yv = 0.3731763325901154f * zz * (5.0f * z2 - 3.0f); break;
                case 13: yv = 0.4570457994644658f * xx * (5.0f * z2 - 1.0f); break;
                case 14: yv = 1.445305721320277f * zz * (x2 - y2); break;
                default: yv = 0.5900435899266435f * xx * (x2 - 3.0f * y2); break;
            }
            Y_sh[pp][sub] = yv;
            if (sub < 4) wal_sh[pp][sub] = W_alch[sj * 4 + sub];
        }
        __syncthreads();
        int base = half * 8;
#pragma unroll
        for (int pq = 0; pq < 8; pq++) {
            int pp2 = base + pq;
            float Re = 0.f;
            const float* rw = raw_sh[pp2];
            const float* wv = &wr2[nn * 4 + l_of];
#pragma unroll
            for (int rr = 0; rr < 16; rr++)
                Re = fmaf(rw[rr], wv[rr * 32], Re);
            float contrib = Y_sh[pp2][lm] * Re;
            const float* wa = wal_sh[pp2];
            acc0 = fmaf(wa[0], contrib, acc0);
            acc1 = fmaf(wa[1], contrib, acc1);
            acc2 = fmaf(wa[2], contrib, acc2);
            acc3 = fmaf(wa[3], contrib, acc3);
        }
        __syncthreads();
    }

    part[half][0 * 128 + e] = acc0;
    part[half][1 * 128 + e] = acc1;
    part[half][2 * 128 + e] = acc2;
    part[half][3 * 128 + e] = acc3;
    __syncthreads();
    c_sh[t]       = part[0][t]       + part[1][t];
    c_sh[t + 256] = part[0][t + 256] + part[1][t + 256];
    __syncthreads();

    const float invsq[4] = {1.0f, 0.57735026918962576f, 0.44721359549995794f,
                            0.37796447300922722f};
    int b = t >> 6, n = (t >> 3) & 7, k = t & 7;
    float fv[16];
    float lsum = 0.0f;
#pragma unroll
    for (int ii = 0; ii < 16; ii++) {
        int l = ii >> 2, a = ii & 3;
        int base = l * l;
        float acc = 0.0f;
        int cntm = 2 * l + 1;
        for (int m = 0; m < cntm; m++)
            acc = fmaf(c_sh[a * 128 + (base + m) * 8 + n],
                       c_sh[b * 128 + (base + m) * 8 + k], acc);
        acc *= invsq[l];
        fv[ii] = acc;
        lsum += acc;
    }

    float v = lsum;
#pragma unroll
    for (int o = 1; o < 64; o <<= 1) v += __shfl_xor(v, o, 64);
    int wid = t >> 6, lane = t & 63;
    if (lane == 0) red[wid] = v;
    __syncthreads();
    float mean = (red[0] + red[1] + red[2] + red[3]) * (1.0f / 4096.0f);

    float lss = 0.0f;
#pragma unroll
    for (int ii = 0; ii < 16; ii++) {
        float d = fv[ii] - mean;
        lss += d * d;
    }
    v = lss;
#pragma unroll
    for (int o = 1; o < 64; o <<= 1) v += __shfl_xor(v, o, 64);
    if (lane == 0) red[4 + wid] = v;
    __syncthreads();
    float var = (red[4] + red[5] + red[6] + red[7]) * (1.0f / 4096.0f);
    float rs = rsqrtf(var + 1e-5f);

    unsigned short* Fo = F + (size_t)atom * 4096;
#pragma unroll
    for (int ii = 0; ii < 16; ii++) {
        int ix = ii * 256 + t;
        Fo[ix] = f2bf((fv[ii] - mean) * rs * gamma[ix] + beta[ix]);
    }
}

// ---------------------------------------------------------------------------
// bf16 MFMA GEMM:  C = epilogue(A @ B^T_rows)
//   A: [Mpad][K] bf16 row-major.  B: [Ntot][K] bf16 row-major (pre-transposed
//   weights, n-major).  BM=128, BN=64, BK=64; 4 waves, each 64x32.
//   LDS tiles [rows][64k] with chunk-XOR swizzle (T2), staged via
//   global_load_lds (linear dest + inverse-swizzled global source, rule #21).
//   MODE 1: gcol in [0,1024), q=gcol>>8; silu(alch_scale * acc) -> bf16 H1
//   MODE 2: per-q (blockIdx.z); silu(acc) -> f32 H2
// ---------------------------------------------------------------------------
template<int MODE>
__global__ __launch_bounds__(256) void gemm_mfma(
    const unsigned short* __restrict__ A, const unsigned short* __restrict__ B,
    void* __restrict__ C, int M, int K, long sAq, long sBq,
    const int* __restrict__ species, const float* __restrict__ W_alch,
    int n_atoms)
{
    __shared__ unsigned short As[128 * 64];  // 16 KB
    __shared__ unsigned short Bs[64 * 64];   // 8 KB
    int t = threadIdx.x, w = t >> 6, lane = t & 63;
    int bm = blockIdx.x * 128, bn = blockIdx.y * 64, q = blockIdx.z;

    const unsigned short* Aq = A + (size_t)q * sAq;
    const unsigned short* Bq = B + (size_t)q * sBq;
    int ldab = K * 2;  // row stride in bytes

    // per-lane global source offset implementing the inverse chunk-XOR swizzle
    long srcoff = (long)(lane >> 3) * ldab + (long)(((lane & 7) ^ (lane >> 3)) << 4);
    const char* Ab = (const char*)Aq + (size_t)bm * ldab + srcoff;
    const char* Bb = (const char*)Bq + (size_t)bn * ldab + srcoff;

    int wr = w >> 1, wc = w & 1;
    f32x4 acc[4][2];
#pragma unroll
    for (int i = 0; i < 4; i++)
#pragma unroll
        for (int j = 0; j < 2; j++) acc[i][j] = (f32x4){0.f, 0.f, 0.f, 0.f};

    int l15 = lane & 15, l16 = lane >> 4;
    int rA0 = wr * 64 + l15;
    int rB0 = wc * 32 + l15;
    int cb0 = l16 * 16;
    int swzA = (rA0 & 7) << 4, swzB = (rB0 & 7) << 4;

    for (int k0 = 0; k0 < K; k0 += 64) {
        long kb = (long)k0 * 2;
#pragma unroll
        for (int i = 0; i < 4; i++) {
            int c = w * 4 + i;
            __builtin_amdgcn_global_load_lds(
                (const __attribute__((address_space(1))) unsigned int*)(Ab + (size_t)(c * 8) * ldab + kb),
                (__attribute__((address_space(3))) unsigned int*)(As + c * 512), 16, 0, 0);
        }
#pragma unroll
        for (int i = 0; i < 2; i++) {
            int c = w * 2 + i;
            __builtin_amdgcn_global_load_lds(
                (const __attribute__((address_space(1))) unsigned int*)(Bb + (size_t)(c * 8) * ldab + kb),
                (__attribute__((address_space(3))) unsigned int*)(Bs + c * 512), 16, 0, 0);
        }
        __syncthreads();

        short8v a[4][2], bfr[2][2];
#pragma unroll
        for (int mb = 0; mb < 4; mb++)
#pragma unroll
            for (int kk = 0; kk < 2; kk++) {
                int addr = (rA0 + mb * 16) * 128 + ((cb0 + kk * 64) ^ swzA);
                a[mb][kk] = *(const short8v*)((const char*)As + addr);
            }
#pragma unroll
        for (int nb = 0; nb < 2; nb++)
#pragma unroll
            for (int kk = 0; kk < 2; kk++) {
                int addr = (rB0 + nb * 16) * 128 + ((cb0 + kk * 64) ^ swzB);
                bfr[nb][kk] = *(const short8v*)((const char*)Bs + addr);
            }
#pragma unroll
        for (int kk = 0; kk < 2; kk++)
#pragma unroll
            for (int mb = 0; mb < 4; mb++)
#pragma unroll
                for (int nb = 0; nb < 2; nb++)
                    acc[mb][nb] = __builtin_amdgcn_mfma_f32_16x16x32_bf16(
                        a[mb][kk], bfr[nb][kk], acc[mb][nb], 0, 0, 0);
        __syncthreads();
    }

    int colbase = bn + wc * 32 + l15;
#pragma unroll
    for (int mb = 0; mb < 4; mb++) {
#pragma unroll
        for (int j = 0; j < 4; j++) {
            int row = bm + wr * 64 + mb * 16 + l16 * 4 + j;
            if (row >= M) continue;
            if (MODE == 1) {
                int sp = species[row];
#pragma unroll
                for (int nb = 0; nb < 2; nb++) {
                    int gcol = colbase + nb * 16;
                    int qq = gcol >> 8, hc = gcol & 255;
                    float v = acc[mb][nb][j] * W_alch[sp * 4 + qq];
                    v = v / (1.0f + expf(-v));
                    ((unsigned short*)C)[((size_t)qq * 4096 + row) * 256 + hc] = f2bf(v);
                }
            } else {
#pragma unroll
                for (int nb = 0; nb < 2; nb++) {
                    int gcol = colbase + nb * 16;
                    float v = acc[mb][nb][j];
                    v = v / (1.0f + expf(-v));
                    ((float*)C)[((size_t)q * n_atoms + row) * 256 + gcol] = v;
                }
            }
        }
    }
}

// ---------------------------------------------------------------------------
// Final: e[n] = sum_q H2[q][n][:].W_last[q][:], += comp_w, segment-sum, *0.5
// ---------------------------------------------------------------------------
__global__ __launch_bounds__(256) void final_kernel(
    const float* __restrict__ H2, const float* __restrict__ W_last,
    const float* __restrict__ comp_w, const int* __restrict__ species,
    const int* __restrict__ sid, float* __restrict__ out, int n_atoms)
{
    int wid = threadIdx.x >> 6, lane = threadIdx.x & 63;
    int atom = blockIdx.x * 4 + wid;
    if (atom >= n_atoms) return;
    float acc = 0.0f;
#pragma unroll
    for (int q = 0; q < 4; q++) {
        const float* h = H2 + ((size_t)q * n_atoms + atom) * 256;
#pragma unroll
        for (int c = 0; c < 4; c++) {
            int hh = c * 64 + lane;
            acc = fmaf(h[hh], W_last[q * 256 + hh], acc);
        }
    }
#pragma unroll
    for (int o = 1; o < 64; o <<= 1) acc += __shfl_xor(acc, o, 64);
    if (lane == 0) {
        float vv = acc + comp_w[species[atom]];
        atomicAdd(&out[sid[atom]], vv * 0.5f);
    }
}

// ---------------------------------------------------------------------------
extern "C" void kernel_launch(void* const* d_in, const int* in_sizes, int n_in,
                              void* d_out, int out_size, void* d_ws, size_t ws_size,
                              hipStream_t stream)
{
    const float* pos     = (const float*)d_in[0];
    const int*   pairs   = (const int*)d_in[1];
    const int*   species = (const int*)d_in[2];
    const int*   sid     = (const int*)d_in[3];
    const float* W_rad   = (const float*)d_in[4];
    const float* W_alch  = (const float*)d_in[5];
    const float* gamma   = (const float*)d_in[6];
    const float* beta    = (const float*)d_in[7];
    const float* W1      = (const float*)d_in[8];
    const float* W2      = (const float*)d_in[9];
    const float* W_last  = (const float*)d_in[10];
    const float* comp_w  = (const float*)d_in[11];

    int n_atoms = in_sizes[0] / 3;   // 4000
    int n_pairs = in_sizes[1] / 2;   // 160000
    float* out = (float*)d_out;

    char* ws = (char*)d_ws;
    int*   cnt    = (int*)(ws);
    int*   cursor = (int*)(ws + 16384);
    int*   off    = (int*)(ws + 32768);
    int*   idx    = (int*)(ws + 49152);
    size_t o1 = 49152 + 640 * 1024;                 // after idx
    unsigned short* W1T = (unsigned short*)(ws + o1);            // 1024x4096 bf16 = 8.39MB
    size_t o2 = o1 + (size_t)1024 * 4096 * 2;
    unsigned short* W2T = (unsigned short*)(ws + o2);            // 4x256x256 bf16 = 0.52MB
    size_t o3 = o2 + (size_t)4 * 256 * 256 * 2;
    unsigned short* Fb  = (unsigned short*)(ws + o3);            // 4096x4096 bf16 = 33.5MB
    size_t o4 = o3 + (size_t)4096 * 4096 * 2;
    unsigned short* H1  = (unsigned short*)(ws + o4);            // 4x4096x256 bf16 = 8.39MB
    size_t o5 = o4 + (size_t)4 * 4096 * 256 * 2;
    float* H2 = (float*)(ws + o5);                               // 4x4000x256 f32 = 16.4MB

    hipMemsetAsync(cnt, 0, 32768, stream);                       // cnt + cursor
    hipMemsetAsync(out, 0, (size_t)out_size * sizeof(float), stream);
    // zero F pad rows [4000,4096) and all of H1 (pad rows feed GEMM2 A-reads)
    hipMemsetAsync(Fb + (size_t)n_atoms * 4096, 0,
                   (size_t)(4096 - n_atoms) * 4096 * 2, stream);
    hipMemsetAsync(H1, 0, (size_t)4 * 4096 * 256 * 2, stream);

    count_kernel<<<(n_pairs + 255) / 256, 256, 0, stream>>>(pairs, cnt, n_pairs);
    scan_kernel<<<1, 256, 0, stream>>>(cnt, off, n_atoms);
    fill_kernel<<<(n_pairs + 255) / 256, 256, 0, stream>>>(pairs, off, cursor, idx, n_pairs);

    transpose_w<<<dim3(4096 / 64, 256 / 64, 4), 256, 0, stream>>>(W1, W1T, 4096, 256);
    transpose_w<<<dim3(256 / 64, 256 / 64, 4), 256, 0, stream>>>(W2, W2T, 256, 256);

    gather_atom_kernel<<<n_atoms, 256, 0, stream>>>(
        pos, pairs, species, W_rad, W_alch, off, idx, gamma, beta, Fb,
        n_atoms, n_pairs);

    // GEMM1: Fb [4096pad x 4096] @ W1T [1024 x 4096]^T -> H1 (bf16, q-split)
    gemm_mfma<1><<<dim3(32, 16, 1), 256, 0, stream>>>(
        Fb, W1T, H1, n_atoms, 4096, 0L, 0L, species, W_alch, n_atoms);

    // GEMM2: H1[q] [4096pad x 256] @ W2T[q] [256 x 256]^T -> H2 (f32)
    gemm_mfma<2><<<dim3(32, 4, 4), 256, 0, stream>>>(
        H1, W2T, H2, n_atoms, 256, 4096L * 256, 256L * 256, species, W_alch, n_atoms);

    final_kernel<<<(n_atoms + 3) / 4, 256, 0, stream>>>(
        H2, W_last, comp_w, species, sid, out, n_atoms);
}